// Round 13
// baseline (1040.914 us; speedup 1.0000x reference)
//
#include <hip/hip_runtime.h>

#define BB 1024
#define TT 512
#define KK 64
#define NEGV -10000.0f

typedef _Float16 h2 __attribute__((ext_vector_type(2)));

#if defined(__has_builtin)
#if __has_builtin(__builtin_amdgcn_fdot2)
#define HAVE_FDOT2 1
#endif
#endif

static __device__ __forceinline__ float dot2_acc(h2 a, h2 b, float c) {
#ifdef HAVE_FDOT2
    return __builtin_amdgcn_fdot2(a, b, c, false);
#else
    return fmaf((float)a.x, (float)b.x, fmaf((float)a.y, (float)b.y, c));
#endif
}

static __device__ __forceinline__ h2 bc_h2(float f) {
    return __builtin_bit_cast(h2, f);
}

// ---------------------------------------------------------------------------
// R13: TWO batches per wave (dual-issue ILP). R6's proven per-batch pipeline
// duplicated with suffixes A/B inside one instruction stream; tr/Er_pk are
// batch-independent and shared (96 VGPRs amortized). Each batch's LDS
// write->read latency chain hides under the other batch's VALU work.
// Grid 512 = 2 blocks/CU x 256 CU, LDS 66 KB/block -> all blocks resident.
// All numerics bitwise-identical to R6 (absmax 0.0).
// ---------------------------------------------------------------------------

#define GOLD(S, BIDX)                                                        \
    float gold##S = 0.f;                                                     \
    {                                                                        \
        const int* tg = tags + (size_t)(BIDX) * TT;                          \
        _Pragma("unroll")                                                    \
        for (int i = 0; i < TT / 64; ++i) {                                  \
            int t = lane + i * 64;                                           \
            int nxt = tg[t];                                                 \
            int prv = t ? tg[t - 1] : 0;                                     \
            gold##S += trans[nxt * KK + prv] +                               \
                       feats[((size_t)(BIDX) * TT + t) * KK + nxt];          \
        }                                                                    \
        if (lane == 0) gold##S += trans[(KK - 1) * KK + tg[TT - 1]];         \
        _Pragma("unroll")                                                    \
        for (int d = 1; d < 64; d <<= 1) gold##S += __shfl_xor(gold##S, d);  \
    }

#define BINIT(S, BIDX)                                                       \
    float a##S = (lane == 0) ? 0.f : NEGV;                                   \
    float wlast##S = a##S;                                                   \
    wa##S[lane] = a##S;                                                      \
    float refUse##S = 0.f, refMid##S = 6.f, refNew##S = 12.f;                \
    const float* fb##S = feats + (size_t)(BIDX) * TT * KK + lane;            \
    float f0##S = fb##S[0 * KK], f1##S = fb##S[1 * KK];                      \
    float f2##S = fb##S[2 * KK], f3##S = fb##S[3 * KK];                      \
    const float* fp##S = fb##S + 4 * KK;                                     \
    float4 p_wa0##S = {}, p_wa1##S = {}, p_tg0##S = {}, p_tg1##S = {};       \
    float p_m##S = 0.f;                                                      \
    int p_base##S = 0;

#define FINISH(S, TROW)                                                      \
    {                                                                        \
        int bpv = p_base##S;                                                 \
        float vv;                                                            \
        vv = p_wa1##S.w + p_tg1##S.w; if (vv == p_m##S) bpv = p_base##S + 7; \
        vv = p_wa1##S.z + p_tg1##S.z; if (vv == p_m##S) bpv = p_base##S + 6; \
        vv = p_wa1##S.y + p_tg1##S.y; if (vv == p_m##S) bpv = p_base##S + 5; \
        vv = p_wa1##S.x + p_tg1##S.x; if (vv == p_m##S) bpv = p_base##S + 4; \
        vv = p_wa0##S.w + p_tg0##S.w; if (vv == p_m##S) bpv = p_base##S + 3; \
        vv = p_wa0##S.z + p_tg0##S.z; if (vv == p_m##S) bpv = p_base##S + 2; \
        vv = p_wa0##S.y + p_tg0##S.y; if (vv == p_m##S) bpv = p_base##S + 1; \
        vv = p_wa0##S.x + p_tg0##S.x; if (vv == p_m##S) bpv = p_base##S + 0; \
        bp##S[TROW][lane] = (unsigned char)bpv;                              \
    }

#define RING(S)                                                              \
    const float f_cur##S = f0##S;                                            \
    f0##S = f1##S; f1##S = f2##S; f2##S = f3##S;                             \
    f3##S = *fp##S;                                                          \
    if (t + 5 < TT) fp##S += KK;

#define EAPUB(S)                                                             \
    ea##S[lane] = (_Float16)__expf(fminf(a##S - refUse##S, 11.0f));

#define GM(S)                                                                \
    float gm##S[8];                                                          \
    {                                                                        \
        const float4* wb = reinterpret_cast<const float4*>(wa##S);           \
        _Pragma("unroll")                                                    \
        for (int g = 0; g < 8; ++g) {                                        \
            float4 wx = wb[2 * g];                                           \
            float4 wy = wb[2 * g + 1];                                       \
            float c0 = wx.x + tr[8 * g + 0];                                 \
            float c1 = wx.y + tr[8 * g + 1];                                 \
            float c2 = wx.z + tr[8 * g + 2];                                 \
            float c3 = wx.w + tr[8 * g + 3];                                 \
            float c4 = wy.x + tr[8 * g + 4];                                 \
            float c5 = wy.y + tr[8 * g + 5];                                 \
            float c6 = wy.z + tr[8 * g + 6];                                 \
            float c7 = wy.w + tr[8 * g + 7];                                 \
            gm##S[g] = fmaxf(fmaxf(fmaxf(c0, c1), fmaxf(c2, c3)),            \
                             fmaxf(fmaxf(c4, c5), fmaxf(c6, c7)));           \
        }                                                                    \
    }

#define FDOT(S)                                                              \
    float ssum##S;                                                           \
    {                                                                        \
        const float4* eb = reinterpret_cast<const float4*>(ea##S);           \
        float pp[8];                                                         \
        _Pragma("unroll")                                                    \
        for (int q = 0; q < 8; ++q) {                                        \
            float4 e4 = eb[q];                                               \
            float acc = 0.f;                                                 \
            acc = dot2_acc(bc_h2(e4.x), Er_pk[4 * q + 0], acc);              \
            acc = dot2_acc(bc_h2(e4.y), Er_pk[4 * q + 1], acc);              \
            acc = dot2_acc(bc_h2(e4.z), Er_pk[4 * q + 2], acc);              \
            acc = dot2_acc(bc_h2(e4.w), Er_pk[4 * q + 3], acc);              \
            pp[q] = acc;                                                     \
        }                                                                    \
        ssum##S = ((pp[0] + pp[1]) + (pp[2] + pp[3])) +                      \
                  ((pp[4] + pp[5]) + (pp[6] + pp[7]));                       \
    }

#define ANEW(S)                                                              \
    {                                                                        \
        float a_new = __logf(ssum##S) + refUse##S + f_cur##S;                \
        refUse##S = refMid##S;                                               \
        refMid##S = refNew##S;                                               \
        refNew##S = __shfl(a_new, 8) + 5.0f;                                 \
        a##S = a_new;                                                        \
    }

#define SELDEF(S)                                                            \
    {                                                                        \
        float m = fmaxf(                                                     \
            fmaxf(fmaxf(gm##S[0], gm##S[1]), fmaxf(gm##S[2], gm##S[3])),     \
            fmaxf(fmaxf(gm##S[4], gm##S[5]), fmaxf(gm##S[6], gm##S[7])));    \
        int g = 0;                                                           \
        _Pragma("unroll")                                                    \
        for (int j = 7; j >= 0; --j)                                         \
            if (gm##S[j] == m) g = j;                                        \
        const int base = g * 8;                                              \
        const float4* wam = reinterpret_cast<const float4*>(wa##S + base);   \
        p_wa0##S = wam[0];                                                   \
        p_wa1##S = wam[1];                                                   \
        wa##S[lane] = m + f_cur##S;                                          \
        const float4* trg =                                                  \
            reinterpret_cast<const float4*>(trans + lane * KK + base);       \
        p_tg0##S = trg[0];                                                   \
        p_tg1##S = trg[1];                                                   \
        p_m##S = m;                                                          \
        p_base##S = base;                                                    \
        wlast##S = m + f_cur##S;                                             \
    }

#define EPILOG(S, BIDX)                                                      \
    {                                                                        \
        float v = a##S + t63;                                                \
        float mm = v;                                                        \
        _Pragma("unroll")                                                    \
        for (int d = 32; d; d >>= 1) mm = fmaxf(mm, __shfl_xor(mm, d));      \
        float es = __expf(v - mm);                                           \
        _Pragma("unroll")                                                    \
        for (int d = 32; d; d >>= 1) es += __shfl_xor(es, d);                \
        float fscore = mm + __logf(es);                                      \
        float tv = wlast##S + t63;                                           \
        float bvv = tv;                                                      \
        int bidx = lane;                                                     \
        _Pragma("unroll")                                                    \
        for (int d = 1; d < 64; d <<= 1) {                                   \
            float ov = __shfl_xor(bvv, d);                                   \
            int oi = __shfl_xor(bidx, d);                                    \
            bool take = (ov > bvv) || (ov == bvv && oi < bidx);              \
            bvv = take ? ov : bvv;                                           \
            bidx = take ? oi : bidx;                                         \
        }                                                                    \
        if (lane == 0) {                                                     \
            out[BIDX] = fscore - gold##S;                                    \
            out[BB + (BIDX)] = bvv;                                          \
        }                                                                    \
        float* outp = out + 2 * BB + (size_t)(BIDX) * TT;                    \
        int cur = bidx;                                                      \
        float my = 0.f;                                                      \
        for (int tb = TT - 16; tb >= 0; tb -= 16) {                          \
            int r[16];                                                       \
            _Pragma("unroll")                                                \
            for (int j = 0; j < 16; ++j) r[j] = bp##S[tb + j][lane];         \
            _Pragma("unroll")                                                \
            for (int j = 15; j >= 0; --j) {                                  \
                my = (lane == ((tb + j) & 63)) ? (float)cur : my;            \
                cur = __shfl(r[j], cur);                                     \
            }                                                                \
            if ((tb & 63) == 0) outp[tb + lane] = my;                        \
        }                                                                    \
    }

__global__ __launch_bounds__(64, 1) void crf_kernel(const float* __restrict__ feats,
                                                    const int* __restrict__ tags,
                                                    const float* __restrict__ trans,
                                                    float* __restrict__ out) {
    __shared__ unsigned char bpA[TT][KK];           // 32 KB backpointers, batch A
    __shared__ unsigned char bpB[TT][KK];           // 32 KB backpointers, batch B
    __shared__ __align__(16) float waA[KK];         // viterbi alpha broadcast A
    __shared__ __align__(16) float waB[KK];         // viterbi alpha broadcast B
    __shared__ __align__(16) _Float16 eaA[KK];      // exp(alpha - ref) f16, A
    __shared__ __align__(16) _Float16 eaB[KK];      // exp(alpha - ref) f16, B

    const int bA = blockIdx.x * 2;
    const int bB = bA + 1;
    const int lane = threadIdx.x;

    GOLD(A, bA)
    GOLD(B, bB)

    // ---- per-lane transition row (lane = next state), shared A/B ----
    float tr[KK];
    h2 Er_pk[KK / 2];
    {
        const float4* trow = reinterpret_cast<const float4*>(trans + lane * KK);
#pragma unroll
        for (int i = 0; i < KK / 4; ++i) {
            float4 v = trow[i];
            tr[4 * i + 0] = v.x; tr[4 * i + 1] = v.y;
            tr[4 * i + 2] = v.z; tr[4 * i + 3] = v.w;
            h2 lo, hi;
            lo.x = (_Float16)__expf(v.x); lo.y = (_Float16)__expf(v.y);
            hi.x = (_Float16)__expf(v.z); hi.y = (_Float16)__expf(v.w);
            Er_pk[2 * i] = lo;
            Er_pk[2 * i + 1] = hi;
        }
    }
    const float t63 = trans[(KK - 1) * KK + lane];  // trans[STOP][lane]

    BINIT(A, bA)
    BINIT(B, bB)

    for (int t = 0; t < TT; ++t) {
        if (t) {
            FINISH(A, t - 1)
            FINISH(B, t - 1)
        }
        RING(A)
        RING(B)
        EAPUB(A)
        EAPUB(B)
        GM(A)
        GM(B)
        FDOT(A)
        FDOT(B)
        ANEW(A)
        ANEW(B)
        SELDEF(A)
        SELDEF(B)
    }
    FINISH(A, TT - 1)
    FINISH(B, TT - 1)

    EPILOG(A, bA)
    EPILOG(B, bB)
}

extern "C" void kernel_launch(void* const* d_in, const int* in_sizes, int n_in,
                              void* d_out, int out_size, void* d_ws, size_t ws_size,
                              hipStream_t stream) {
    const float* feats = (const float*)d_in[0];
    const int* tags = (const int*)d_in[1];
    const float* trans = (const float*)d_in[2];
    float* out = (float*)d_out;

    crf_kernel<<<BB / 2, 64, 0, stream>>>(feats, tags, trans, out);
}

// Round 14
// 351.286 us; speedup vs baseline: 2.9632x; 2.9632x over previous
//
#include <hip/hip_runtime.h>

#define BB 1024
#define TT 512
#define KK 64
#define NEGV -10000.0f

typedef _Float16 h2 __attribute__((ext_vector_type(2)));

#if defined(__has_builtin)
#if __has_builtin(__builtin_amdgcn_fdot2)
#define HAVE_FDOT2 1
#endif
#endif

static __device__ __forceinline__ float dot2_acc(h2 a, h2 b, float c) {
#ifdef HAVE_FDOT2
    return __builtin_amdgcn_fdot2(a, b, c, false);
#else
    return fmaf((float)a.x, (float)b.x, fmaf((float)a.y, (float)b.y, c));
#endif
}

static __device__ __forceinline__ h2 bc_h2(float f) {
    return __builtin_bit_cast(h2, f);
}

// ---------------------------------------------------------------------------
// crf_kernel (R6 structure -- best measured: 351 us headline, 385 profiled,
// reproduced twice). ONE wave per batch, forward and Viterbi recurrences
// MERGED in one instruction stream: the two chains are independent within a
// step, so each hides the other's DS/VALU latency. Deferred argmax epilogue:
// operand re-reads for step t's backpointer (wa_buf LDS row + trans global
// row, bitwise-identical sources) are issued at the end of step t, consumed
// at the top of step t+1 -- a full iteration of latency cover, no live c[64].
//   - forward: f16 ea broadcast + v_dot2, 2-step-pipelined wave-uniform ref
//   - viterbi: exact fp32 adds / commutative maxes; descending equality scans
//     give first-index tie-breaks (absmax 0.0 verified)
//   - feats prefetch ring depth 4; bp in LDS; shfl-chain backtrace
//   - gold score folded into the block prologue
// 14-round evidence: every structural alternative (2-wave split, 4-wave coop,
// DPP broadcasts x3, DS trims, dual-batch ILP, register-only epilogue) is
// 13%-4.6x slower. Floor = VALU issue (~990 cyc/step) + DS-pipe/LDS-RT chain
// (~800 cyc/step exposed) at grid-capped 1 wave/SIMD (1024 batches).
// ---------------------------------------------------------------------------
__global__ __launch_bounds__(64, 1) void crf_kernel(const float* __restrict__ feats,
                                                    const int* __restrict__ tags,
                                                    const float* __restrict__ trans,
                                                    float* __restrict__ out) {
    __shared__ unsigned char bp[TT][KK];            // 32 KB backpointers
    __shared__ __align__(16) float wa_buf[KK];      // viterbi alpha broadcast
    __shared__ __align__(16) _Float16 ea_buf[KK];   // exp(alpha - ref), f16

    const int b = blockIdx.x;
    const int lane = threadIdx.x;

    // ---- gold score (one-time, lane-parallel gather) ----
    const int* tg = tags + (size_t)b * TT;
    float gold = 0.f;
#pragma unroll
    for (int i = 0; i < TT / 64; ++i) {
        int t = lane + i * 64;
        int nxt = tg[t];
        int prv = t ? tg[t - 1] : 0;
        gold += trans[nxt * KK + prv] + feats[((size_t)b * TT + t) * KK + nxt];
    }
    if (lane == 0) gold += trans[(KK - 1) * KK + tg[TT - 1]];  // STOP term
#pragma unroll
    for (int d = 1; d < 64; d <<= 1) gold += __shfl_xor(gold, d);

    // ---- per-lane transition row (lane = next state) ----
    float tr[KK];
    h2 Er_pk[KK / 2];   // exp(tr) packed f16 pairs for the forward dot2
    {
        const float4* trow = reinterpret_cast<const float4*>(trans + lane * KK);
#pragma unroll
        for (int i = 0; i < KK / 4; ++i) {
            float4 v = trow[i];
            tr[4 * i + 0] = v.x; tr[4 * i + 1] = v.y;
            tr[4 * i + 2] = v.z; tr[4 * i + 3] = v.w;
            h2 lo, hi;
            lo.x = (_Float16)__expf(v.x); lo.y = (_Float16)__expf(v.y);
            hi.x = (_Float16)__expf(v.z); hi.y = (_Float16)__expf(v.w);
            Er_pk[2 * i] = lo;
            Er_pk[2 * i + 1] = hi;
        }
    }
    const float t63 = trans[(KK - 1) * KK + lane];  // trans[STOP][lane]

    float a = (lane == 0) ? 0.f : NEGV;   // forward alpha (log domain)
    float w = a;                          // viterbi alpha (lane = state)
    wa_buf[lane] = w;
    // pipelined wave-uniform normalizer: refUse(t) = shfl(a_{t-2}, 8) + 5
    float refUse = 0.f, refMid = 6.f, refNew = 12.f;

    // feats prefetch ring, depth 4
    const float* fbp = feats + (size_t)b * TT * KK + lane;
    float f0 = fbp[0 * KK];
    float f1 = fbp[1 * KK];
    float f2 = fbp[2 * KK];
    float f3 = fbp[3 * KK];
    const float* fp = fbp + 4 * KK;

    // pending (deferred) epilogue state for step t-1
    float4 p_wa0 = {}, p_wa1 = {}, p_tg0 = {}, p_tg1 = {};
    float p_m = 0.f;
    int p_base = 0;

    for (int t = 0; t < TT; ++t) {
        // ---- finish step t-1: argmax compare + bp store (operands have had a
        //      full iteration of latency cover) ----
        if (t) {
            int bpv = p_base;
            float vv;
            vv = p_wa1.w + p_tg1.w; if (vv == p_m) bpv = p_base + 7;
            vv = p_wa1.z + p_tg1.z; if (vv == p_m) bpv = p_base + 6;
            vv = p_wa1.y + p_tg1.y; if (vv == p_m) bpv = p_base + 5;
            vv = p_wa1.x + p_tg1.x; if (vv == p_m) bpv = p_base + 4;
            vv = p_wa0.w + p_tg0.w; if (vv == p_m) bpv = p_base + 3;
            vv = p_wa0.z + p_tg0.z; if (vv == p_m) bpv = p_base + 2;
            vv = p_wa0.y + p_tg0.y; if (vv == p_m) bpv = p_base + 1;
            vv = p_wa0.x + p_tg0.x; if (vv == p_m) bpv = p_base + 0;
            bp[t - 1][lane] = (unsigned char)bpv;
        }

        const float f_cur = f0;
        f0 = f1; f1 = f2; f2 = f3;
        f3 = *fp;                       // row min(t+4, TT-1)
        if (t + 5 < TT) fp += KK;

        // ======== forward: publish normalized exp(alpha), f16 ========
        float x = fminf(a - refUse, 11.0f);     // e^11 < f16 max
        ea_buf[lane] = (_Float16)__expf(x);
        // single-wave block: in-order DS pipe, no barrier needed

        // ======== viterbi: candidates + group maxima (no c[] kept) ========
        float gm[8];
        const float4* wb = reinterpret_cast<const float4*>(wa_buf);
#pragma unroll
        for (int g = 0; g < 8; ++g) {
            float4 wA = wb[2 * g];
            float4 wB = wb[2 * g + 1];
            float c0 = wA.x + tr[8 * g + 0];
            float c1 = wA.y + tr[8 * g + 1];
            float c2 = wA.z + tr[8 * g + 2];
            float c3 = wA.w + tr[8 * g + 3];
            float c4 = wB.x + tr[8 * g + 4];
            float c5 = wB.y + tr[8 * g + 5];
            float c6 = wB.z + tr[8 * g + 6];
            float c7 = wB.w + tr[8 * g + 7];
            gm[g] = fmaxf(fmaxf(fmaxf(c0, c1), fmaxf(c2, c3)),
                          fmaxf(fmaxf(c4, c5), fmaxf(c6, c7)));
        }

        // ======== forward: dot-products over the broadcast ========
        const float4* eb = reinterpret_cast<const float4*>(ea_buf);
        float s0 = 0.f, s1 = 0.f, s2 = 0.f, s3 = 0.f;
        float s4 = 0.f, s5 = 0.f, s6 = 0.f, s7 = 0.f;
#pragma unroll
        for (int q = 0; q < 8; ++q) {
            float4 e4 = eb[q];
            float acc = 0.f;
            acc = dot2_acc(bc_h2(e4.x), Er_pk[4 * q + 0], acc);
            acc = dot2_acc(bc_h2(e4.y), Er_pk[4 * q + 1], acc);
            acc = dot2_acc(bc_h2(e4.z), Er_pk[4 * q + 2], acc);
            acc = dot2_acc(bc_h2(e4.w), Er_pk[4 * q + 3], acc);
            switch (q) {   // 8 independent chains
                case 0: s0 = acc; break; case 1: s1 = acc; break;
                case 2: s2 = acc; break; case 3: s3 = acc; break;
                case 4: s4 = acc; break; case 5: s5 = acc; break;
                case 6: s6 = acc; break; case 7: s7 = acc; break;
            }
        }
        float s = ((s0 + s1) + (s2 + s3)) + ((s4 + s5) + (s6 + s7));
        float a_new = __logf(s) + refUse + f_cur;
        refUse = refMid;
        refMid = refNew;
        refNew = __shfl(a_new, 8) + 5.0f;   // consumed 2 iterations later
        a = a_new;

        // ======== viterbi: max, group select, issue deferred loads ========
        float m = fmaxf(fmaxf(fmaxf(gm[0], gm[1]), fmaxf(gm[2], gm[3])),
                        fmaxf(fmaxf(gm[4], gm[5]), fmaxf(gm[6], gm[7])));
        int g = 0;
#pragma unroll
        for (int j = 7; j >= 0; --j)   // descending: smallest matching group
            if (gm[j] == m) g = j;
        const int base = g * 8;

        // re-reads consumed NEXT iteration; wa reads BEFORE the write (old vals)
        const float4* wam = reinterpret_cast<const float4*>(wa_buf + base);
        p_wa0 = wam[0];
        p_wa1 = wam[1];
        wa_buf[lane] = m + f_cur;           // in-order DS pipe: reads saw old
        const float4* trg = reinterpret_cast<const float4*>(trans + lane * KK + base);
        p_tg0 = trg[0];
        p_tg1 = trg[1];                     // L1/L2-resident, full-step cover
        p_m = m;
        p_base = base;
        w = m + f_cur;
    }
    // finish last step's bp
    {
        int bpv = p_base;
        float vv;
        vv = p_wa1.w + p_tg1.w; if (vv == p_m) bpv = p_base + 7;
        vv = p_wa1.z + p_tg1.z; if (vv == p_m) bpv = p_base + 6;
        vv = p_wa1.y + p_tg1.y; if (vv == p_m) bpv = p_base + 5;
        vv = p_wa1.x + p_tg1.x; if (vv == p_m) bpv = p_base + 4;
        vv = p_wa0.w + p_tg0.w; if (vv == p_m) bpv = p_base + 3;
        vv = p_wa0.z + p_tg0.z; if (vv == p_m) bpv = p_base + 2;
        vv = p_wa0.y + p_tg0.y; if (vv == p_m) bpv = p_base + 1;
        vv = p_wa0.x + p_tg0.x; if (vv == p_m) bpv = p_base + 0;
        bp[TT - 1][lane] = (unsigned char)bpv;
    }

    // ---- forward score: exact logsumexp(alpha_T + trans[STOP][:]) ----
    float v = a + t63;
    float mm = v;
#pragma unroll
    for (int d = 32; d; d >>= 1) mm = fmaxf(mm, __shfl_xor(mm, d));
    float es = __expf(v - mm);
#pragma unroll
    for (int d = 32; d; d >>= 1) es += __shfl_xor(es, d);
    float fscore = mm + __logf(es);

    // ---- viterbi terminal: max + first-index argmax (exact) ----
    float tv = w + t63;
    float bvv = tv;
    int bidx = lane;
#pragma unroll
    for (int d = 1; d < 64; d <<= 1) {
        float ov = __shfl_xor(bvv, d);
        int oi = __shfl_xor(bidx, d);
        bool take = (ov > bvv) || (ov == bvv && oi < bidx);
        bvv = take ? ov : bvv;
        bidx = take ? oi : bidx;
    }

    if (lane == 0) {
        out[b] = fscore - gold;
        out[BB + b] = bvv;
    }

    // ---- backtrace: bulk LDS row loads + dynamic-shfl chain ----
    float* outp = out + 2 * BB + (size_t)b * TT;
    int cur = bidx;                 // wave-uniform
    float my = 0.f;                 // latched path values (lane = t & 63)
    for (int tb = TT - 16; tb >= 0; tb -= 16) {
        int r[16];
#pragma unroll
        for (int j = 0; j < 16; ++j) r[j] = bp[tb + j][lane];
#pragma unroll
        for (int j = 15; j >= 0; --j) {
            my = (lane == ((tb + j) & 63)) ? (float)cur : my;
            cur = __shfl(r[j], cur);
        }
        if ((tb & 63) == 0) outp[tb + lane] = my;   // coalesced 64-wide store
    }
}

extern "C" void kernel_launch(void* const* d_in, const int* in_sizes, int n_in,
                              void* d_out, int out_size, void* d_ws, size_t ws_size,
                              hipStream_t stream) {
    const float* feats = (const float*)d_in[0];
    const int* tags = (const int*)d_in[1];
    const float* trans = (const float*)d_in[2];
    float* out = (float*)d_out;

    crf_kernel<<<BB, 64, 0, stream>>>(feats, tags, trans, out);
}